// Round 11
// baseline (365.013 us; speedup 1.0000x reference)
//
#include <hip/hip_runtime.h>

// LSTM B=4096, T=512, I=1, H=64, O=1 (fp32 in/out).
// Round 11: K-PACKED hi/lo, MB=16, grid=256 (EXACTLY 1 block/CU — kills the
// 2-blocks-per-CU placement lottery diagnosed in r10: occupancy 18.7%<25%
// means some CUs carried 3 blocks, setting the tail).
// h stored interleaved per batch row: [b][2u]=hi, [2u+1]=lo (f16). K=128;
// B-fragments duplicate each weight into both k-slots -> gate=Σw*(hi+lo),
// exact. M rows = 16 REAL batches (no hi/lo in M): 16 MFMA/wave-step for 16
// batches (1/batch, zero redundancy), 4 cells/lane (all lanes productive),
// NO acc pair-sums, h-write = 4 packed ds_write_b32 (hi|lo in one u32).
// Wave w owns tiles {w,w+4,w+8,w+12} -> lane (l16,h0) gets all 4 gates of
// unit j=16w+l16 for batches 4h0..4h0+3 in its 16 acc regs.
// Math (r10): exp2 pre-scaled weights, shared reciprocals now PAIRED across
// cells: rcp(P0*P1) serves 2 cells (P<=2^51.5, product<2^103: safe) ->
// 5 exp2 + 1 rcp per cell. x*w_ih+bias via MFMA C operand, pipelined.
// MFMA layouts (m89-verified): A[m=lane&15][k=(lane>>4)*8+i],
// B[k=(lane>>4)*8+i][n=lane&15], D[m=(lane>>4)*4+r][n=lane&15].

#define TT   512
#define HPW  136           // f16 row stride (272 B = 17*16: 16B-aligned)
#define BUFE (16 * HPW)    // one ping-pong buffer: 16 batch rows
#define SXP  20            // sh_x row stride (floats; mult of 4 for b128 reads)

#define L2E  1.4426950408889634f
#define L2E2 2.8853900817779268f

typedef _Float16 f16x8 __attribute__((ext_vector_type(8)));
typedef float    f32x4 __attribute__((ext_vector_type(4)));

#define MFMA16(a, b, c) __builtin_amdgcn_mfma_f32_16x16x32_f16((a), (b), (c), 0, 0, 0)

__device__ __forceinline__ float rcp_(float x)  { return __builtin_amdgcn_rcpf(x); }
__device__ __forceinline__ float exp2_(float x) { return __builtin_amdgcn_exp2f(x); }

__global__ __launch_bounds__(256, 1) void lstm_kp(
    const float* __restrict__ x,      // [4096, 512]
    const float* __restrict__ w_ih,   // [256]
    const float* __restrict__ w_hh,   // [256, 64]
    const float* __restrict__ b_ih,   // [256]
    const float* __restrict__ b_hh,   // [256]
    const float* __restrict__ w_out,  // [64]
    const float* __restrict__ b_out,  // [1]
    float* __restrict__ out)          // [4096]
{
    __shared__ __align__(16) float    sh_x[TT * SXP];   // [t][batch], 40 KB
    __shared__ __align__(16) _Float16 hbuf[2 * BUFE];   // ping-pong, 8.5 KB

    const int tid = threadIdx.x;
    const int w   = tid >> 6;    // wave 0..3: owns tiles {w, w+4, w+8, w+12}
    const int L   = tid & 63;
    const int l16 = L & 15;
    const int h0  = L >> 4;      // 0..3
    const int b0  = blockIdx.x * 16;
    const int j   = 16 * w + l16;  // hidden unit owned by this lane

    // ---- stage x: sh_x[t*SXP + m] = x[b0+m][t], m=0..15 (float4 coalesced) ----
    {
        const int half = tid >> 7;
        const int l    = tid & 127;
        const int t0   = 4 * l;
        #pragma unroll
        for (int q8 = 0; q8 < 8; ++q8) {
            const int q = q8 + 8 * half;
            float4 v = *(const float4*)(x + (size_t)(b0 + q) * TT + t0);
            sh_x[(t0 + 0) * SXP + q] = v.x;
            sh_x[(t0 + 1) * SXP + q] = v.y;
            sh_x[(t0 + 2) * SXP + q] = v.z;
            sh_x[(t0 + 3) * SXP + q] = v.w;
        }
    }
    // ---- zero both h buffers ----
    for (int i = tid; i < 2 * BUFE; i += 256) hbuf[i] = (_Float16)0.0f;

    // ---- B-fragments: W fp16-rounded, exp2-prescaled, k-pair duplicated ----
    // chunk c row k=32c+8h0+i -> unit u=(32c+8h0+i)>>1 = 16c+4h0+(i>>1)
    const float sc[4] = {-L2E, -L2E, L2E2, -L2E};
    f16x8 Bf[4][4];
    float wihv[4], biasv[4];
    #pragma unroll
    for (int s = 0; s < 4; ++s) {
        const int n = 64 * s + j;
        const float* wr = w_hh + n * 64;
        #pragma unroll
        for (int c = 0; c < 4; ++c) {
            float4 v = *(const float4*)(wr + 16 * c + 4 * h0);
            f16x8 b;
            b[0] = b[1] = (_Float16)(v.x * sc[s]);
            b[2] = b[3] = (_Float16)(v.y * sc[s]);
            b[4] = b[5] = (_Float16)(v.z * sc[s]);
            b[6] = b[7] = (_Float16)(v.w * sc[s]);
            Bf[s][c] = b;
        }
        wihv[s]  = w_ih[n] * sc[s];
        biasv[s] = (b_ih[n] + b_hh[n]) * sc[s];
    }

    const int aoff = l16 * HPW + 8 * h0;  // A-frag base (f16); chunks +32c
    const int wcol = 2 * j;               // packed hi|lo column

    float cc[4] = {0.f, 0.f, 0.f, 0.f};
    __syncthreads();

    // C-operand pipeline: ci[s][r] = x[batch 4h0+r]*w_ih + bias
    f32x4 ci[4];
    {
        float4 xq = *(const float4*)(sh_x + 4 * h0);
        #pragma unroll
        for (int s = 0; s < 4; ++s) {
            ci[s][0] = fmaf(xq.x, wihv[s], biasv[s]);
            ci[s][1] = fmaf(xq.y, wihv[s], biasv[s]);
            ci[s][2] = fmaf(xq.z, wihv[s], biasv[s]);
            ci[s][3] = fmaf(xq.w, wihv[s], biasv[s]);
        }
    }

    auto step = [&](const _Float16* rb, _Float16* wb, int t) {
        f16x8 A0 = *(const f16x8*)(rb + aoff);
        f16x8 A1 = *(const f16x8*)(rb + aoff + 32);
        f16x8 A2 = *(const f16x8*)(rb + aoff + 64);
        f16x8 A3 = *(const f16x8*)(rb + aoff + 96);

        f32x4 acc[4];
        #pragma unroll
        for (int s = 0; s < 4; ++s)
            acc[s] = MFMA16(A3, Bf[s][3],
                     MFMA16(A2, Bf[s][2],
                     MFMA16(A1, Bf[s][1],
                     MFMA16(A0, Bf[s][0], ci[s]))));

        // refresh ci for t+1 in the MFMA shadow (h-independent)
        if (t + 1 < TT) {
            float4 xq = *(const float4*)(sh_x + (t + 1) * SXP + 4 * h0);
            #pragma unroll
            for (int s = 0; s < 4; ++s) {
                ci[s][0] = fmaf(xq.x, wihv[s], biasv[s]);
                ci[s][1] = fmaf(xq.y, wihv[s], biasv[s]);
                ci[s][2] = fmaf(xq.z, wihv[s], biasv[s]);
                ci[s][3] = fmaf(xq.w, wihv[s], biasv[s]);
            }
        }

        // ---- 4 cells/lane; reciprocals paired across cells {0,1},{2,3} ----
        float P[4], DfDg[4], DiDg[4], DiDf[4], Eo[4];
        #pragma unroll
        for (int r = 0; r < 4; ++r) {
            float Di = 1.0f + exp2_(acc[0][r]);
            float Df = 1.0f + exp2_(acc[1][r]);
            float Dg = 1.0f + exp2_(acc[2][r]);
            Eo[r]   = exp2_(acc[3][r]);
            DfDg[r] = Df * Dg;
            DiDg[r] = Di * Dg;
            DiDf[r] = Di * Df;
            P[r]    = Di * DfDg[r];
        }
        const float u01 = rcp_(P[0] * P[1]);
        const float u23 = rcp_(P[2] * P[3]);
        const float inv[4] = {u01 * P[1], u01 * P[0], u23 * P[3], u23 * P[2]};
        float Dc[4], Do[4], Q[4];
        #pragma unroll
        for (int r = 0; r < 4; ++r) {
            float si = DfDg[r] * inv[r];
            float sf = DiDg[r] * inv[r];
            float tg = fmaf(-2.0f, DiDf[r] * inv[r], 1.0f);
            cc[r] = fmaf(sf, cc[r], si * tg);
            float Ec = exp2_(fminf(cc[r] * L2E2, 30.0f));
            Dc[r] = 1.0f + Ec;
            Do[r] = 1.0f + Eo[r];
            Q[r]  = Do[r] * Dc[r];
        }
        const float v01 = rcp_(Q[0] * Q[1]);
        const float v23 = rcp_(Q[2] * Q[3]);
        const float invQ[4] = {v01 * Q[1], v01 * Q[0], v23 * Q[3], v23 * Q[2]};
        #pragma unroll
        for (int r = 0; r < 4; ++r) {
            float hv = (invQ[r] * Dc[r]) * fmaf(-2.0f, invQ[r] * Do[r], 1.0f);
            _Float16 hh = (_Float16)hv;
            _Float16 hl = (_Float16)(hv - (float)hh);
            union { _Float16 h2[2]; unsigned int u; } pk;
            pk.h2[0] = hh;   // hi plane at even index 2j
            pk.h2[1] = hl;   // lo plane at 2j+1
            *(unsigned int*)(wb + (4 * h0 + r) * HPW + wcol) = pk.u;
        }
        __syncthreads();
    };

    for (int t = 0; t < TT; t += 2) {
        step(hbuf,        hbuf + BUFE, t);      // read buf0, write buf1
        step(hbuf + BUFE, hbuf,        t + 1);  // read buf1, write buf0
    }

    // ---- epilogue: final h in buf0; wave w reduces batches 4w..4w+3 ----
    const float wo = w_out[L];
    #pragma unroll
    for (int p = 0; p < 4; ++p) {
        const int b = 4 * w + p;
        float hvf = (float)hbuf[b * HPW + 2 * L] + (float)hbuf[b * HPW + 2 * L + 1];
        float v = hvf * wo;
        #pragma unroll
        for (int off = 32; off; off >>= 1) v += __shfl_down(v, off);
        if (L == 0) out[b0 + b] = v + b_out[0];
    }
}

extern "C" void kernel_launch(void* const* d_in, const int* in_sizes, int n_in,
                              void* d_out, int out_size, void* d_ws, size_t ws_size,
                              hipStream_t stream) {
    const float* x     = (const float*)d_in[0];
    const float* w_ih  = (const float*)d_in[1];
    const float* w_hh  = (const float*)d_in[2];
    const float* b_ih  = (const float*)d_in[3];
    const float* b_hh  = (const float*)d_in[4];
    const float* w_out = (const float*)d_in[5];
    const float* b_out = (const float*)d_in[6];
    float* out = (float*)d_out;

    lstm_kp<<<256, 256, 0, stream>>>(x, w_ih, w_hh, b_ih, b_hh,
                                     w_out, b_out, out);
}

// Round 12
// 341.231 us; speedup vs baseline: 1.0697x; 1.0697x over previous
//
#include <hip/hip_runtime.h>

// LSTM B=4096, T=512, I=1, H=64, O=1 (fp32 in/out).
// Round 12: DUAL FREE-RUNNING GROUPS, 1 block/CU guaranteed.
// Block = 512 thr (8 waves), grid = 256 (= #CUs: no 2-blocks/CU placement
// lottery, r10's diagnosis). Group g = waves {4g..4g+3} handles 8 batches;
// wave i sits on SIMD i&3 -> EVERY SIMD hosts one wave of EACH group.
// Groups sync internally via an LDS flag counter (atomicAdd + acquire spin
// + s_sleep) -- never with each other -> group 1, skewed ~576 cyc at start,
// free-runs anti-phase to group 0: each SIMD's two waves alternate
// compute/stall, hiding the serial chain (r11 showed 1 wave/SIMD exposes
// ~740 cyc idle; r9 showed 2 waves/SIMD + stagger cuts it to ~445).
// Per-wave structure = r9/r10 (proven): M-packed hi/lo h (row 2q=hi, 2q+1=lo
// of batch q), 8 MFMA/wave-step, all 4 gates of a cell colocated in one
// lane's acc regs (2 cells/lane), zero shuffles; r10 math: exp2-prescaled
// weights, shared reciprocals (7 trans/cell), x*w_ih+bias as MFMA C operand
// refreshed in the MFMA shadow. Ping-pong h buffers per group.
// MFMA layouts (m89-verified): A[m=lane&15][k=(lane>>4)*8+i],
// B[k=(lane>>4)*8+i][n=lane&15], D[m=(lane>>4)*4+r][n=lane&15].

#define TT   512
#define HP   72            // f16 row stride (144 B): 16B-aligned, 2-way max
#define BUFE (16 * HP)     // one ping-pong buffer: 16 rows
#define SXP  18            // sh_x row stride (floats), even (b64-aligned)

#define L2E  1.4426950408889634f
#define L2E2 2.8853900817779268f

typedef _Float16 f16x8 __attribute__((ext_vector_type(8)));
typedef float    f32x4 __attribute__((ext_vector_type(4)));

#define MFMA16(a, b, c) __builtin_amdgcn_mfma_f32_16x16x32_f16((a), (b), (c), 0, 0, 0)

__device__ __forceinline__ float rcp_(float x)  { return __builtin_amdgcn_rcpf(x); }
__device__ __forceinline__ float exp2_(float x) { return __builtin_amdgcn_exp2f(x); }

__device__ __forceinline__ f16x8 cvt8s(const float4& u0, const float4& u1, float s) {
    f16x8 r;
    r[0] = (_Float16)(u0.x * s); r[1] = (_Float16)(u0.y * s);
    r[2] = (_Float16)(u0.z * s); r[3] = (_Float16)(u0.w * s);
    r[4] = (_Float16)(u1.x * s); r[5] = (_Float16)(u1.y * s);
    r[6] = (_Float16)(u1.z * s); r[7] = (_Float16)(u1.w * s);
    return r;
}

__global__ __launch_bounds__(512, 2) void lstm_fs(
    const float* __restrict__ x,      // [4096, 512]
    const float* __restrict__ w_ih,   // [256]
    const float* __restrict__ w_hh,   // [256, 64]
    const float* __restrict__ b_ih,   // [256]
    const float* __restrict__ b_hh,   // [256]
    const float* __restrict__ w_out,  // [64]
    const float* __restrict__ b_out,  // [1]
    float* __restrict__ out)          // [4096]
{
    __shared__ __align__(16) float    sh_x[TT * SXP];      // [t][m16], 36.9 KB
    __shared__ __align__(16) _Float16 hbuf[2][2][BUFE];    // [group][pp], 9.2 KB
    __shared__ unsigned int           flag[2];             // per-group step counter

    const int tid = threadIdx.x;
    const int g   = tid >> 8;          // group 0/1 (batches 8g..8g+7)
    const int w4  = (tid >> 6) & 3;    // wave within group: owns N-tiles {w4,w4+4,w4+8,w4+12}
    const int L   = tid & 63;
    const int l16 = L & 15;
    const int h0  = L >> 4;            // 0..3
    const int b0  = blockIdx.x * 16;
    const int j   = 16 * w4 + l16;     // hidden unit col owned by this lane

    // ---- stage x: sh_x[t*SXP + m] = x[b0+m][t], m=0..15 (coalesced) ----
    {
        const int q = tid >> 5;        // batch 0..15
        const int l = tid & 31;
        const float* xr = x + (size_t)(b0 + q) * TT;
        #pragma unroll
        for (int i = 0; i < TT / 32; ++i)
            sh_x[(l + 32 * i) * SXP + q] = xr[l + 32 * i];
    }
    // ---- zero all h buffers; init flags ----
    for (int i = tid; i < 2 * 2 * BUFE; i += 512) (&hbuf[0][0][0])[i] = (_Float16)0.0f;
    if (tid < 2) flag[tid] = 0u;

    // ---- preload W_hh fragments, exp2-prescaled (r10) ----
    const float sc[4] = {-L2E, -L2E, L2E2, -L2E};
    f16x8 Bf[4][2];
    float wihv[4], biasv[4];
    #pragma unroll
    for (int s = 0; s < 4; ++s) {
        const int n = 64 * s + j;
        #pragma unroll
        for (int kt = 0; kt < 2; ++kt) {
            const float* p = w_hh + n * 64 + kt * 32 + h0 * 8;
            float4 u0 = *(const float4*)p;
            float4 u1 = *(const float4*)(p + 4);
            Bf[s][kt] = cvt8s(u0, u1, sc[s]);
        }
        wihv[s]  = w_ih[n] * sc[s];
        biasv[s] = (b_ih[n] + b_hh[n]) * sc[s];
    }

    const int aoff = l16 * HP + 8 * h0;    // A-frag base (f16); +32 for chunk 1
    const int xoff = 8 * g + 2 * h0;       // this lane's batch pair in sh_x
    const int wr   = 4 * h0 * HP + j;      // h-write base (rows 4h0..4h0+3)

    float cc0 = 0.0f, cc1 = 0.0f;

    // shared-rcp cell update (r10, proven absmax 4.9e-4)
    auto cellup = [&](float ai, float af, float ag, float ao, float& cc) -> float {
        float Ei = exp2_(ai), Ef = exp2_(af), Eg = exp2_(ag);
        float Di = 1.0f + Ei, Df = 1.0f + Ef, Dg = 1.0f + Eg;
        float Pif = Di * Df;
        float u   = rcp_(Pif * Dg);
        float si  = u * (Df * Dg);
        float sf  = u * (Di * Dg);
        float tg  = fmaf(-2.0f, u * Pif, 1.0f);
        cc = fmaf(sf, cc, si * tg);
        float Ec = exp2_(fminf(cc * L2E2, 30.0f));
        float Eo = exp2_(ao);
        float Dc = 1.0f + Ec, Do = 1.0f + Eo;
        float u2 = rcp_(Do * Dc);
        return (u2 * Dc) * fmaf(-2.0f, u2 * Do, 1.0f);
    };

    __syncthreads();   // staging + zeroing + flags visible to all

    // ---- anti-phase: group 1 starts ~576 cyc late and free-runs there ----
    if (g) __builtin_amdgcn_s_sleep(9);

    // C-operand pipeline
    f32x4 ci[4];
    {
        const float2 x0 = *(const float2*)(sh_x + xoff);
        #pragma unroll
        for (int s = 0; s < 4; ++s) {
            ci[s][0] = fmaf(x0.x, wihv[s], biasv[s]);
            ci[s][1] = 0.0f;
            ci[s][2] = fmaf(x0.y, wihv[s], biasv[s]);
            ci[s][3] = 0.0f;
        }
    }

    for (int t = 0; t < TT; ++t) {
        const _Float16* rb = hbuf[g][t & 1];
        _Float16*       wb = hbuf[g][(t + 1) & 1];

        f16x8 a0 = *(const f16x8*)(rb + aoff);
        f16x8 a1 = *(const f16x8*)(rb + aoff + 32);

        f32x4 acc[4];
        #pragma unroll
        for (int s = 0; s < 4; ++s)
            acc[s] = MFMA16(a1, Bf[s][1], MFMA16(a0, Bf[s][0], ci[s]));

        // refresh ci for t+1 in the MFMA shadow (h-independent)
        {
            const int tn = (t + 1 < TT) ? (t + 1) : t;
            const float2 xn = *(const float2*)(sh_x + tn * SXP + xoff);
            #pragma unroll
            for (int s = 0; s < 4; ++s) {
                ci[s][0] = fmaf(xn.x, wihv[s], biasv[s]);
                ci[s][2] = fmaf(xn.y, wihv[s], biasv[s]);
            }
        }

        // cell 0: batch 8g+2h0 (arg = hi row + lo row)
        {
            float hv = cellup(acc[0][0] + acc[0][1], acc[1][0] + acc[1][1],
                              acc[2][0] + acc[2][1], acc[3][0] + acc[3][1], cc0);
            _Float16 hh = (_Float16)hv;
            wb[wr]      = hh;
            wb[wr + HP] = (_Float16)(hv - (float)hh);
        }
        // cell 1: batch 8g+2h0+1
        {
            float hv = cellup(acc[0][2] + acc[0][3], acc[1][2] + acc[1][3],
                              acc[2][2] + acc[2][3], acc[3][2] + acc[3][3], cc1);
            _Float16 hh = (_Float16)hv;
            wb[wr + 2 * HP] = hh;
            wb[wr + 3 * HP] = (_Float16)(hv - (float)hh);
        }

        // ---- group-local 4-wave flag barrier (groups stay decoupled) ----
        __threadfence_block();                     // drain h writes
        if (L == 0) atomicAdd(&flag[g], 1u);
        const unsigned int tgt = 4u * (unsigned)(t + 1);
        while (__hip_atomic_load(&flag[g], __ATOMIC_ACQUIRE,
                                 __HIP_MEMORY_SCOPE_WORKGROUP) < tgt)
            __builtin_amdgcn_s_sleep(1);
    }

    __syncthreads();   // join both groups before epilogue

    // ---- epilogue: final h in pp=0; wave W reduces batches 2W, 2W+1 ----
    const int W = tid >> 6;
    const float wo = w_out[L];
    #pragma unroll
    for (int p = 0; p < 2; ++p) {
        const int m  = 2 * W + p;       // block-local batch 0..15
        const int gm = m >> 3, q = m & 7;
        float hvf = (float)hbuf[gm][0][(2 * q) * HP + L]
                  + (float)hbuf[gm][0][(2 * q + 1) * HP + L];
        float v = hvf * wo;
        #pragma unroll
        for (int off = 32; off; off >>= 1) v += __shfl_down(v, off);
        if (L == 0) out[b0 + m] = v + b_out[0];
    }
}

extern "C" void kernel_launch(void* const* d_in, const int* in_sizes, int n_in,
                              void* d_out, int out_size, void* d_ws, size_t ws_size,
                              hipStream_t stream) {
    const float* x     = (const float*)d_in[0];
    const float* w_ih  = (const float*)d_in[1];
    const float* w_hh  = (const float*)d_in[2];
    const float* b_ih  = (const float*)d_in[3];
    const float* b_hh  = (const float*)d_in[4];
    const float* w_out = (const float*)d_in[5];
    const float* b_out = (const float*)d_in[6];
    float* out = (float*)d_out;

    lstm_fs<<<256, 512, 0, stream>>>(x, w_ih, w_hh, b_ih, b_hh,
                                     w_out, b_out, out);
}

// Round 13
// 317.042 us; speedup vs baseline: 1.1513x; 1.0763x over previous
//
#include <hip/hip_runtime.h>

// LSTM B=4096, T=512, I=1, H=64, O=1 (fp32 in/out).
// Round 13 = r9/r10 structure (best: 292us steady) + busy cuts:
//  (1) h stored as PLAIN fp16 (lo-plane dropped). Odd M-rows stay zero;
//      gates = acc[s][0] / acc[s][2] directly (no pair-adds). absmax has been
//      pinned at 2^-11 by fp16 W-rounding, so h-rounding of the same
//      magnitude should land ~1e-3 < 2.8e-3 threshold.
//  (2) paired reciprocals across the lane's 2 cells (r11 scheme, overflow
//      safe: P0P1<=2^77, Q0Q1<=2^88): 6 trans/cell (5 exp2 + 1 rcp).
//  (3) exp2-prescaled weights, x*w_ih+bias as MFMA C operand refreshed in
//      the MFMA shadow (r10), stagger retuned to s_sleep(9) (~576 cyc).
// Structure: MB=8, grid=512 (2 blocks/CU, s_barrier, stagger). M-rows:
// row 2q = h[batch q] (fp16), row 2q+1 = 0. 8 MFMA/wave-step; all 4 gates
// of a cell in one lane's acc regs (2 cells/lane); one barrier/step;
// ping-pong h buffers.
// MFMA layouts (m89-verified): A[m=lane&15][k=(lane>>4)*8+i],
// B[k=(lane>>4)*8+i][n=lane&15], D[m=(lane>>4)*4+r][n=lane&15].

#define TT   512
#define MB   8
#define HP   72            // f16 row stride (144 B): 16B-aligned, 2-way max
#define BUFE (16 * HP)     // one ping-pong buffer: 16 rows
#define SXP  10            // sh_x row stride (floats)

#define L2E  1.4426950408889634f
#define L2E2 2.8853900817779268f

typedef _Float16 f16x8 __attribute__((ext_vector_type(8)));
typedef float    f32x4 __attribute__((ext_vector_type(4)));

#define MFMA16(a, b, c) __builtin_amdgcn_mfma_f32_16x16x32_f16((a), (b), (c), 0, 0, 0)

__device__ __forceinline__ float rcp_(float x)  { return __builtin_amdgcn_rcpf(x); }
__device__ __forceinline__ float exp2_(float x) { return __builtin_amdgcn_exp2f(x); }

__device__ __forceinline__ f16x8 cvt8s(const float4& u0, const float4& u1, float s) {
    f16x8 r;
    r[0] = (_Float16)(u0.x * s); r[1] = (_Float16)(u0.y * s);
    r[2] = (_Float16)(u0.z * s); r[3] = (_Float16)(u0.w * s);
    r[4] = (_Float16)(u1.x * s); r[5] = (_Float16)(u1.y * s);
    r[6] = (_Float16)(u1.z * s); r[7] = (_Float16)(u1.w * s);
    return r;
}

__global__ __launch_bounds__(256, 2) void lstm_mfma(
    const float* __restrict__ x,      // [4096, 512]
    const float* __restrict__ w_ih,   // [256]
    const float* __restrict__ w_hh,   // [256, 64]
    const float* __restrict__ b_ih,   // [256]
    const float* __restrict__ b_hh,   // [256]
    const float* __restrict__ w_out,  // [64]
    const float* __restrict__ b_out,  // [1]
    float* __restrict__ out)          // [4096]
{
    __shared__ __align__(16) float    sh_x[TT * SXP];   // [t][m], 20 KB
    __shared__ __align__(16) _Float16 hbuf[2 * BUFE];   // 4.6 KB

    const int tid = threadIdx.x;
    const int w   = tid >> 6;    // wave 0..3 (owns N-tiles {w, w+4, w+8, w+12})
    const int L   = tid & 63;
    const int l16 = L & 15;
    const int h0  = L >> 4;      // 0..3
    const int b0  = blockIdx.x * MB;
    const int j   = 16 * w + l16;  // hidden unit col owned by this lane

    // ---- stage x: sh_x[t*SXP + m] = x[b0+m][t] (coalesced) ----
    {
        const int q = tid >> 5;   // batch 0..7
        const int l = tid & 31;
        const float* xr = x + (size_t)(b0 + q) * TT;
        #pragma unroll
        for (int i = 0; i < TT / 32; ++i)
            sh_x[(l + 32 * i) * SXP + q] = xr[l + 32 * i];
    }
    // ---- zero both h buffers (odd rows stay zero forever) ----
    for (int i = tid; i < 2 * BUFE; i += 256) hbuf[i] = (_Float16)0.0f;

    // ---- preload W_hh fragments, exp2-prescaled ----
    const float sc[4] = {-L2E, -L2E, L2E2, -L2E};
    f16x8 Bf[4][2];
    float wihv[4], biasv[4];
    #pragma unroll
    for (int s = 0; s < 4; ++s) {
        const int n = 64 * s + j;
        #pragma unroll
        for (int kt = 0; kt < 2; ++kt) {
            const float* p = w_hh + n * 64 + kt * 32 + h0 * 8;
            float4 u0 = *(const float4*)p;
            float4 u1 = *(const float4*)(p + 4);
            Bf[s][kt] = cvt8s(u0, u1, sc[s]);
        }
        wihv[s]  = w_ih[n] * sc[s];
        biasv[s] = (b_ih[n] + b_hh[n]) * sc[s];
    }

    // lane's A row m=l16: batch l16>>1 if l16 even (odd rows zero)
    const int aoff = l16 * HP + h0 * 8;   // f16 units; +32 for K-chunk 1
    // lane's cells: batches 2h0, 2h0+1 -> h rows 4h0 (cell0), 4h0+2 (cell1)
    const int xoff = 2 * h0;
    const int wr   = 4 * h0 * HP + j;

    float cc0 = 0.0f, cc1 = 0.0f;

    // C-operand pipeline: rows 0,2 = x*w_ih+bias for batches 2h0, 2h0+1
    f32x4 ci[4];
    {
        const float2 x0 = *(const float2*)(sh_x + xoff);
        #pragma unroll
        for (int s = 0; s < 4; ++s) {
            ci[s][0] = fmaf(x0.x, wihv[s], biasv[s]);
            ci[s][1] = 0.0f;
            ci[s][2] = fmaf(x0.y, wihv[s], biasv[s]);
            ci[s][3] = 0.0f;
        }
    }

    __syncthreads();

    // ---- phase stagger: desync co-resident blocks by ~half a step ----
    if (((blockIdx.x >> 8) ^ blockIdx.x) & 1) {
        __builtin_amdgcn_s_sleep(9);   // ~576 cyc
    }

    auto step = [&](const _Float16* rb, _Float16* wb, int t) {
        f16x8 a0 = *(const f16x8*)(rb + aoff);
        f16x8 a1 = *(const f16x8*)(rb + aoff + 32);

        f32x4 acc[4];
        #pragma unroll
        for (int s = 0; s < 4; ++s)
            acc[s] = MFMA16(a1, Bf[s][1], MFMA16(a0, Bf[s][0], ci[s]));

        // refresh ci for t+1 in the MFMA shadow (h-independent)
        if (t + 1 < TT) {
            const float2 xn = *(const float2*)(sh_x + (t + 1) * SXP + xoff);
            #pragma unroll
            for (int s = 0; s < 4; ++s) {
                ci[s][0] = fmaf(xn.x, wihv[s], biasv[s]);
                ci[s][2] = fmaf(xn.y, wihv[s], biasv[s]);
            }
        }

        // ---- dual-cell update, paired reciprocals (6 trans/cell) ----
        // cell0 args: acc[s][0]; cell1 args: acc[s][2]
        float Ei0 = exp2_(acc[0][0]), Ef0 = exp2_(acc[1][0]);
        float Eg0 = exp2_(acc[2][0]), Eo0 = exp2_(acc[3][0]);
        float Ei1 = exp2_(acc[0][2]), Ef1 = exp2_(acc[1][2]);
        float Eg1 = exp2_(acc[2][2]), Eo1 = exp2_(acc[3][2]);
        float Di0 = 1.0f + Ei0, Df0 = 1.0f + Ef0, Dg0 = 1.0f + Eg0, Do0 = 1.0f + Eo0;
        float Di1 = 1.0f + Ei1, Df1 = 1.0f + Ef1, Dg1 = 1.0f + Eg1, Do1 = 1.0f + Eo1;

        float FG0 = Df0 * Dg0, IG0 = Di0 * Dg0, IF0 = Di0 * Df0;
        float FG1 = Df1 * Dg1, IG1 = Di1 * Dg1, IF1 = Di1 * Df1;
        float P0 = Di0 * FG0, P1 = Di1 * FG1;
        float u  = rcp_(P0 * P1);
        float inv0 = u * P1, inv1 = u * P0;

        float si0 = FG0 * inv0, sf0 = IG0 * inv0;
        float tg0 = fmaf(-2.0f, IF0 * inv0, 1.0f);
        cc0 = fmaf(sf0, cc0, si0 * tg0);
        float si1 = FG1 * inv1, sf1 = IG1 * inv1;
        float tg1 = fmaf(-2.0f, IF1 * inv1, 1.0f);
        cc1 = fmaf(sf1, cc1, si1 * tg1);

        float Ec0 = exp2_(fminf(cc0 * L2E2, 30.0f));
        float Ec1 = exp2_(fminf(cc1 * L2E2, 30.0f));
        float Dc0 = 1.0f + Ec0, Dc1 = 1.0f + Ec1;
        float Q0 = Do0 * Dc0, Q1 = Do1 * Dc1;
        float v  = rcp_(Q0 * Q1);
        float iq0 = v * Q1, iq1 = v * Q0;
        float hv0 = (iq0 * Dc0) * fmaf(-2.0f, iq0 * Do0, 1.0f);
        float hv1 = (iq1 * Dc1) * fmaf(-2.0f, iq1 * Do1, 1.0f);

        wb[wr]          = (_Float16)hv0;   // row 4h0   (batch 2h0)
        wb[wr + 2 * HP] = (_Float16)hv1;   // row 4h0+2 (batch 2h0+1)
        __syncthreads();
    };

    for (int t = 0; t < TT; t += 2) {
        step(hbuf,        hbuf + BUFE, t);      // read buf0, write buf1
        step(hbuf + BUFE, hbuf,        t + 1);  // read buf1, write buf0
    }

    // ---- epilogue: final h in buf0; wave w reduces batches 2w, 2w+1 ----
    const float wo = w_out[L];
    #pragma unroll
    for (int p = 0; p < 2; ++p) {
        const int q = 2 * w + p;
        float v = (float)hbuf[(2 * q) * HP + L] * wo;
        #pragma unroll
        for (int off = 32; off; off >>= 1) v += __shfl_down(v, off);
        if (L == 0) out[b0 + q] = v + b_out[0];
    }
}

extern "C" void kernel_launch(void* const* d_in, const int* in_sizes, int n_in,
                              void* d_out, int out_size, void* d_ws, size_t ws_size,
                              hipStream_t stream) {
    const float* x     = (const float*)d_in[0];
    const float* w_ih  = (const float*)d_in[1];
    const float* w_hh  = (const float*)d_in[2];
    const float* b_ih  = (const float*)d_in[3];
    const float* b_hh  = (const float*)d_in[4];
    const float* w_out = (const float*)d_in[5];
    const float* b_out = (const float*)d_in[6];
    float* out = (float*)d_out;

    lstm_mfma<<<4096 / MB, 256, 0, stream>>>(x, w_ih, w_hh, b_ih, b_hh,
                                             w_out, b_out, out);
}

// Round 14
// 307.278 us; speedup vs baseline: 1.1879x; 1.0318x over previous
//
#include <hip/hip_runtime.h>

// LSTM B=4096, T=512, I=1, H=64, O=1 (fp32 in/out).
// Round 14 = r13 (best: 284.5us steady) + PACKED fp32 cell math:
//  The lane's two cells (batches 2h0, 2h0+1) are evaluated as float2
//  ext-vectors -> clang emits v_pk_add/mul/fma_f32 (VOP3P dual fp32):
//  halves the plain-VALU term (~400 cyc/SIMD-step, the largest busy term).
//  exp2/rcp remain scalar (no packed transcendentals; count unchanged:
//  5 exp2 + 1 rcp per cell via cross-cell shared reciprocals).
//  Stagger retuned to s_sleep(10) (~640 cyc ~ half the predicted step).
// Structure (r13): MB=8, grid=512 (2 blocks/CU, s_barrier, stagger).
// h stored plain fp16 in even M rows (row 2q = h[batch q], odd rows zero);
// 8 MFMA/wave-step; all 4 gates of a cell in one lane's acc regs (2 cells
// per lane); exp2-prescaled weights; x*w_ih+bias as MFMA C operand
// refreshed in the MFMA shadow; one barrier/step; ping-pong h buffers.
// MFMA layouts (m89-verified): A[m=lane&15][k=(lane>>4)*8+i],
// B[k=(lane>>4)*8+i][n=lane&15], D[m=(lane>>4)*4+r][n=lane&15].

#define TT   512
#define MB   8
#define HP   72            // f16 row stride (144 B): 16B-aligned, 2-way max
#define BUFE (16 * HP)     // one ping-pong buffer: 16 rows
#define SXP  10            // sh_x row stride (floats)

#define L2E  1.4426950408889634f
#define L2E2 2.8853900817779268f

typedef _Float16 f16x8 __attribute__((ext_vector_type(8)));
typedef float    f32x4 __attribute__((ext_vector_type(4)));
typedef float    f32x2 __attribute__((ext_vector_type(2)));

#define MFMA16(a, b, c) __builtin_amdgcn_mfma_f32_16x16x32_f16((a), (b), (c), 0, 0, 0)

__device__ __forceinline__ float rcp_(float x)  { return __builtin_amdgcn_rcpf(x); }
__device__ __forceinline__ float exp2_(float x) { return __builtin_amdgcn_exp2f(x); }

__device__ __forceinline__ f16x8 cvt8s(const float4& u0, const float4& u1, float s) {
    f16x8 r;
    r[0] = (_Float16)(u0.x * s); r[1] = (_Float16)(u0.y * s);
    r[2] = (_Float16)(u0.z * s); r[3] = (_Float16)(u0.w * s);
    r[4] = (_Float16)(u1.x * s); r[5] = (_Float16)(u1.y * s);
    r[6] = (_Float16)(u1.z * s); r[7] = (_Float16)(u1.w * s);
    return r;
}

__global__ __launch_bounds__(256, 2) void lstm_mfma(
    const float* __restrict__ x,      // [4096, 512]
    const float* __restrict__ w_ih,   // [256]
    const float* __restrict__ w_hh,   // [256, 64]
    const float* __restrict__ b_ih,   // [256]
    const float* __restrict__ b_hh,   // [256]
    const float* __restrict__ w_out,  // [64]
    const float* __restrict__ b_out,  // [1]
    float* __restrict__ out)          // [4096]
{
    __shared__ __align__(16) float    sh_x[TT * SXP];   // [t][m], 20 KB
    __shared__ __align__(16) _Float16 hbuf[2 * BUFE];   // 4.6 KB

    const int tid = threadIdx.x;
    const int w   = tid >> 6;    // wave 0..3 (owns N-tiles {w, w+4, w+8, w+12})
    const int L   = tid & 63;
    const int l16 = L & 15;
    const int h0  = L >> 4;      // 0..3
    const int b0  = blockIdx.x * MB;
    const int j   = 16 * w + l16;  // hidden unit col owned by this lane

    // ---- stage x: sh_x[t*SXP + m] = x[b0+m][t] (coalesced) ----
    {
        const int q = tid >> 5;   // batch 0..7
        const int l = tid & 31;
        const float* xr = x + (size_t)(b0 + q) * TT;
        #pragma unroll
        for (int i = 0; i < TT / 32; ++i)
            sh_x[(l + 32 * i) * SXP + q] = xr[l + 32 * i];
    }
    // ---- zero both h buffers (odd rows stay zero forever) ----
    for (int i = tid; i < 2 * BUFE; i += 256) hbuf[i] = (_Float16)0.0f;

    // ---- preload W_hh fragments, exp2-prescaled ----
    const float sc[4] = {-L2E, -L2E, L2E2, -L2E};
    f16x8 Bf[4][2];
    float wihv[4], biasv[4];
    #pragma unroll
    for (int s = 0; s < 4; ++s) {
        const int n = 64 * s + j;
        #pragma unroll
        for (int kt = 0; kt < 2; ++kt) {
            const float* p = w_hh + n * 64 + kt * 32 + h0 * 8;
            float4 u0 = *(const float4*)p;
            float4 u1 = *(const float4*)(p + 4);
            Bf[s][kt] = cvt8s(u0, u1, sc[s]);
        }
        wihv[s]  = w_ih[n] * sc[s];
        biasv[s] = (b_ih[n] + b_hh[n]) * sc[s];
    }

    // lane's A row m=l16: batch l16>>1 if l16 even (odd rows zero)
    const int aoff = l16 * HP + h0 * 8;   // f16 units; +32 for K-chunk 1
    // lane's cells: batches 2h0, 2h0+1 -> h rows 4h0 (cell0), 4h0+2 (cell1)
    const int xoff = 2 * h0;
    const int wr   = 4 * h0 * HP + j;

    f32x2 ccv = {0.0f, 0.0f};   // c-state of the lane's two cells

    // C-operand pipeline: rows 0,2 = x*w_ih+bias for batches 2h0, 2h0+1
    f32x4 ci[4];
    {
        const float2 x0 = *(const float2*)(sh_x + xoff);
        #pragma unroll
        for (int s = 0; s < 4; ++s) {
            ci[s][0] = fmaf(x0.x, wihv[s], biasv[s]);
            ci[s][1] = 0.0f;
            ci[s][2] = fmaf(x0.y, wihv[s], biasv[s]);
            ci[s][3] = 0.0f;
        }
    }

    __syncthreads();

    // ---- phase stagger: desync co-resident blocks by ~half a step ----
    if (((blockIdx.x >> 8) ^ blockIdx.x) & 1) {
        __builtin_amdgcn_s_sleep(10);   // ~640 cyc
    }

    auto step = [&](const _Float16* rb, _Float16* wb, int t) {
        f16x8 a0 = *(const f16x8*)(rb + aoff);
        f16x8 a1 = *(const f16x8*)(rb + aoff + 32);

        f32x4 acc[4];
        #pragma unroll
        for (int s = 0; s < 4; ++s)
            acc[s] = MFMA16(a1, Bf[s][1], MFMA16(a0, Bf[s][0], ci[s]));

        // refresh ci for t+1 in the MFMA shadow (h-independent, packed fma)
        if (t + 1 < TT) {
            const float2 xn = *(const float2*)(sh_x + (t + 1) * SXP + xoff);
            const f32x2 xnv = {xn.x, xn.y};
            #pragma unroll
            for (int s = 0; s < 4; ++s) {
                f32x2 c2 = xnv * wihv[s] + biasv[s];   // v_pk_fma_f32
                ci[s][0] = c2[0];
                ci[s][2] = c2[1];
            }
        }

        // ---- dual-cell update as float2 (v_pk_*_f32); trans stay scalar ----
        f32x2 Ei = {exp2_(acc[0][0]), exp2_(acc[0][2])};
        f32x2 Ef = {exp2_(acc[1][0]), exp2_(acc[1][2])};
        f32x2 Eg = {exp2_(acc[2][0]), exp2_(acc[2][2])};
        f32x2 Eo = {exp2_(acc[3][0]), exp2_(acc[3][2])};
        f32x2 Di = Ei + 1.0f, Df = Ef + 1.0f, Dg = Eg + 1.0f, Do = Eo + 1.0f;

        f32x2 FG = Df * Dg, IG = Di * Dg, IF = Di * Df;
        f32x2 P  = Di * FG;
        float u  = rcp_(P[0] * P[1]);
        f32x2 inv = {u * P[1], u * P[0]};

        f32x2 si = FG * inv, sf = IG * inv;
        f32x2 tg = 1.0f - 2.0f * (IF * inv);
        ccv = sf * ccv + si * tg;                       // v_pk_fma_f32

        f32x2 ca = ccv * L2E2;
        f32x2 Ec = {exp2_(fminf(ca[0], 30.0f)), exp2_(fminf(ca[1], 30.0f))};
        f32x2 Dc = Ec + 1.0f;
        f32x2 Q  = Do * Dc;
        float v  = rcp_(Q[0] * Q[1]);
        f32x2 iq = {v * Q[1], v * Q[0]};
        f32x2 hv = (iq * Dc) * (1.0f - 2.0f * (iq * Do));

        wb[wr]          = (_Float16)hv[0];   // row 4h0   (batch 2h0)
        wb[wr + 2 * HP] = (_Float16)hv[1];   // row 4h0+2 (batch 2h0+1)
        __syncthreads();
    };

    for (int t = 0; t < TT; t += 2) {
        step(hbuf,        hbuf + BUFE, t);      // read buf0, write buf1
        step(hbuf + BUFE, hbuf,        t + 1);  // read buf1, write buf0
    }

    // ---- epilogue: final h in buf0; wave w reduces batches 2w, 2w+1 ----
    const float wo = w_out[L];
    #pragma unroll
    for (int p = 0; p < 2; ++p) {
        const int q = 2 * w + p;
        float v = (float)hbuf[(2 * q) * HP + L] * wo;
        #pragma unroll
        for (int off = 32; off; off >>= 1) v += __shfl_down(v, off);
        if (L == 0) out[b0 + q] = v + b_out[0];
    }
}

extern "C" void kernel_launch(void* const* d_in, const int* in_sizes, int n_in,
                              void* d_out, int out_size, void* d_ws, size_t ws_size,
                              hipStream_t stream) {
    const float* x     = (const float*)d_in[0];
    const float* w_ih  = (const float*)d_in[1];
    const float* w_hh  = (const float*)d_in[2];
    const float* b_ih  = (const float*)d_in[3];
    const float* b_hh  = (const float*)d_in[4];
    const float* w_out = (const float*)d_in[5];
    const float* b_out = (const float*)d_in[6];
    float* out = (float*)d_out;

    lstm_mfma<<<4096 / MB, 256, 0, stream>>>(x, w_ih, w_hh, b_ih, b_hh,
                                             w_out, b_out, out);
}